// Round 17
// baseline (3213.035 us; speedup 1.0000x reference)
//
#include <hip/hip_runtime.h>
#include <hip/hip_bf16.h>

// TreeHopNode: h = q - rep + (per-head MLP(sigmoid(Qh*Kh/16)*Vh)) @ Ws
// N=65536, E=1024, H=4, G=256, MLP=256. bf16 MFMA 16x16x32, f32 accum.
//
// R17 = R13 pipeline + g123 (G1+G2+G3 fused) USING R16's proven B-in-regs:
//  - wq/wk/wv/ws packed FRAG-LINEAR; B-frags global->reg, dbuf 1 slice ahead
//  - staging = Aq + Ar only (4 loads/thread/slice) -> 4-slot rotation for
//    BOTH A tensors (128KB LDS), cold gates (R12/R13 proven ledger form)
//  - per phase: 24 MFMA (8 acq + 16 ack/acv) at the SAME barrier count as
//    g23 -> G1's whole dispatch rides the fixed ~1760cy/phase sync cost
//    (R9-R16: that cost is structure-fixed; per-phase work is the dial)
//  - R14's failure isolated to 2-slot hot vmcnt(0) gates; fixed here.
// Gate proof: wave's implicit vmcnt wait on b(s) regs at (s,MH0) drains the
// in-order counter past A(s+1) (older); explicit vmcnt(14)@MH1 = insurance.
// F = gemm_bt (R16, passed). mlp/cvt unchanged (R13, passed).
// Spill canary: WRITE_SIZE must stay 131072 KB on g123.

typedef __attribute__((ext_vector_type(8))) short bf16x8;
typedef __attribute__((ext_vector_type(4))) float f32x4;
typedef __attribute__((ext_vector_type(4))) short short4v;

#define AS1 __attribute__((address_space(1)))
#define AS3 __attribute__((address_space(3)))

static __device__ __forceinline__ short f2b(float x) {
  __hip_bfloat16 h = __float2bfloat16(x);
  return __builtin_bit_cast(short, h);
}
static __device__ __forceinline__ float b2f(short s) {
  unsigned u = ((unsigned)(unsigned short)s) << 16;
  return __builtin_bit_cast(float, u);
}

// ---------------- convert f32 -> bf16 (both inputs, one launch) ----------
__global__ void cvt_bf16_2(const float* __restrict__ q, const float* __restrict__ rep,
                           short* __restrict__ qb, short* __restrict__ rb, long n) {
  const float* __restrict__ in = blockIdx.z ? rep : q;
  short* __restrict__ out = blockIdx.z ? rb : qb;
  long i = ((long)blockIdx.x * blockDim.x + threadIdx.x) * 4;
  const long stride = (long)gridDim.x * blockDim.x * 4;
  for (; i < n; i += stride) {
    float4 v = *(const float4*)(in + i);
    short4v o = { f2b(v.x), f2b(v.y), f2b(v.z), f2b(v.w) };
    *(short4v*)(out + i) = o;
  }
}

// ---------------- transpose + convert weights ----------------
// jobs 0-3 (Wq,Wk,Wv,Ws): FRAGMENT-LINEAR pack (for global-B GEMMs)
// jobs 4-11 (W1,W2 heads): [col][k] transpose (for gemm_mlp)
__global__ void prep_weights(
    const float* __restrict__ Wq, const float* __restrict__ Wk, const float* __restrict__ Wv,
    const float* __restrict__ W1, const float* __restrict__ W2, const float* __restrict__ Ws,
    short* __restrict__ wqt, short* __restrict__ wkt, short* __restrict__ wvt,
    short* __restrict__ w1t, short* __restrict__ w2t, short* __restrict__ wst)
{
  const int job = blockIdx.z;
  const float* src; short* dst; int R, C;
  if (job < 3)       { src = (job==0)?Wq:((job==1)?Wk:Wv); dst = (job==0)?wqt:((job==1)?wkt:wvt); R = 1024; C = 1024; }
  else if (job == 3) { src = Ws; dst = wst; R = 1024; C = 1024; }
  else if (job < 8)  { int h = job-4; src = W1 + h*65536; dst = w1t + h*65536; R = 256; C = 256; }
  else               { int h = job-8; src = W2 + h*65536; dst = w2t + h*65536; R = 256; C = 256; }
  const int c0 = blockIdx.x * 32, r0 = blockIdx.y * 32;
  if (c0 >= C || r0 >= R) return;
  __shared__ float t[32][33];
  for (int i = threadIdx.y; i < 32; i += 8)
    t[i][threadIdx.x] = src[(long)(r0 + i) * C + c0 + threadIdx.x];
  __syncthreads();
  if (job < 4) {
    // frag-linear: idx = (c>>4)*(R/8)*128 + (r>>3)*128 + (c&15)*8 + (r&7)
    for (int i = threadIdx.y; i < 32; i += 8) {
      const int c = c0 + i, r = r0 + threadIdx.x;
      const long idx = (long)(c >> 4) * (R / 8) * 128 + (r >> 3) * 128
                     + ((c & 15) << 3) + (r & 7);
      dst[idx] = f2b(t[threadIdx.x][i]);
    }
  } else {
    for (int i = threadIdx.y; i < 32; i += 8)
      dst[(long)(c0 + i) * R + r0 + threadIdx.x] = f2b(t[threadIdx.x][i]);
  }
}

// ------- 256x256-tile GEMM, A-only LDS (4-slot), B global frag-linear ----
// C = ep(A @ B^T); Bp frag-linear packed. RESID: f32 out = qres-rres+acc.
template <int KDIM, bool RESID>
__global__ __launch_bounds__(512, 2) void gemm_bt(
    const short* __restrict__ A, const short* __restrict__ Bp,
    void* __restrict__ outv,
    const short* __restrict__ qres, const short* __restrict__ rres)
{
  __shared__ __align__(16) short lA[4 * 8192];     // 4 slots of [256][32]
  const int lane = threadIdx.x & 63, wave = threadIdx.x >> 6;
  const int wm = wave >> 2, wn = wave & 3;         // 2M x 4N wave grid
  int bx = blockIdx.x, by = blockIdx.y;
  {
    const int nbx = gridDim.x;
    const int flat = by * nbx + bx;
    const int chunk = (int)(gridDim.x * gridDim.y) >> 3;
    const int fid = (flat & 7) * chunk + (flat >> 3);
    bx = fid % nbx; by = fid / nbx;
  }
  const long bm = (long)by * 256;
  const int  bn = bx * 256;

  const short* Ab = A + bm * 1024;
  constexpr int NS = KDIM / 32;
  const int g0 = lane >> 4;
  const int arow = wm * 128 + (lane & 15);

  const char* aP = (const char*)lA + arow * 64 + (((g0 ^ (arow >> 1)) & 3) << 4);
  const short* bG = Bp + (long)(bn / 16 + wn * 4) * (KDIM / 8) * 128
                      + g0 * 128 + ((lane & 15) << 3);

  const int rw = lane >> 2;
  const int gg = (lane & 3) ^ ((rw >> 1) & 3);
  const short* Asrc = Ab + (wave * 16 + rw) * 1024 + (gg << 3);
  short* lAd = lA + wave * 16 * 32;

  auto stA = [&](int slot, int s) {
    const int sc = s < NS ? s : NS - 1;            // tail: clamp SOURCE only
    const short* src = Asrc + sc * 32;
    short* d = lAd + slot * 8192;
    __builtin_amdgcn_global_load_lds((const AS1 void*)src,              (AS3 void*)d,        16, 0, 0);
    __builtin_amdgcn_global_load_lds((const AS1 void*)(src + 128*1024), (AS3 void*)(d+4096), 16, 0, 0);
  };
  auto ldB = [&](bf16x8* d, int s) {
    const int sc = s < NS ? s : NS - 1;
    #pragma unroll
    for (int j = 0; j < 4; ++j)
      d[j] = *(const bf16x8*)(bG + (long)j * (KDIM / 8) * 128 + sc * 512);
  };

  bf16x8 b0[4], b1[4];
  ldB(b0, 0);
  stA(0, 0); stA(1, 1); stA(2, 2);
  asm volatile("s_waitcnt vmcnt(4)" ::: "memory");
  __builtin_amdgcn_s_barrier();

  f32x4 acc[8][4] = {};

#define PHASE(SLOT, MH, BC, STMT, DOVM)                                     \
  {                                                                         \
    bf16x8 a[4];                                                            \
    _Pragma("unroll")                                                       \
    for (int i2 = 0; i2 < 4; ++i2)                                          \
      a[i2] = *(const bf16x8*)(aP + (SLOT) * 16384 + (MH) * 4096 + i2 * 1024); \
    STMT;                                                                   \
    if (DOVM) asm volatile("s_waitcnt vmcnt(6)" ::: "memory");              \
    asm volatile("" ::: "memory");                                          \
    __builtin_amdgcn_s_barrier();                                           \
    __builtin_amdgcn_s_setprio(1);                                          \
    _Pragma("unroll")                                                       \
    for (int i2 = 0; i2 < 4; ++i2)                                          \
      _Pragma("unroll")                                                     \
      for (int j = 0; j < 4; ++j)                                           \
        acc[(MH) * 4 + i2][j] = __builtin_amdgcn_mfma_f32_16x16x32_bf16(    \
            a[i2], BC[j], acc[(MH) * 4 + i2][j], 0, 0, 0);                  \
    __builtin_amdgcn_s_setprio(0);                                          \
    asm volatile("" ::: "memory");                                          \
    __builtin_amdgcn_s_barrier();                                           \
  }

  for (int s = 0; s < NS; s += 4) {
    PHASE(0, 0, b0, { ldB(b1, s + 1); stA(3, s + 3); }, false) PHASE(0, 1, b0, {}, true)
    PHASE(1, 0, b1, { ldB(b0, s + 2); stA(0, s + 4); }, false) PHASE(1, 1, b1, {}, true)
    PHASE(2, 0, b0, { ldB(b1, s + 3); stA(1, s + 5); }, false) PHASE(2, 1, b0, {}, true)
    PHASE(3, 0, b1, { ldB(b0, s + 4); stA(2, s + 6); }, false) PHASE(3, 1, b1, {}, true)
  }
#undef PHASE

  // epilogue; C/D layout: col=lane&15, row=(lane>>4)*4+reg (m89)
  #pragma unroll
  for (int i = 0; i < 8; ++i)
    #pragma unroll
    for (int j = 0; j < 4; ++j)
      #pragma unroll
      for (int r = 0; r < 4; ++r) {
        const int rl = wm * 128 + i * 16 + ((lane >> 4) << 2) + r;
        const int cl = wn * 64 + j * 16 + (lane & 15);
        const float v = acc[i][j][r];
        const long gi = (bm + rl) * 1024 + bn + cl;
        if (RESID) {
          ((float*)outv)[gi] = b2f(qres[gi]) - b2f(rres[gi]) + v;
        } else {
          ((short*)outv)[gi] = f2b(v);
        }
      }
}

// ---- fused G1+G2+G3: z = sigmoid((q@Wq)*(rep@Wk)/16) * (rep@Wv) --------
// 256x128 tile; Aq,Ar in 4-slot LDS (128KB); Bq/Bk/Bv global frag-linear,
// reg-double-buffered. 24 MFMA/phase at g23's barrier count.
__global__ __launch_bounds__(512, 2) void gemm_g123(
    const short* __restrict__ qb, const short* __restrict__ rb,
    const short* __restrict__ wqt, const short* __restrict__ wkt,
    const short* __restrict__ wvt, short* __restrict__ zb)
{
  __shared__ __align__(16) short lAq[4 * 8192];    // 64KB
  __shared__ __align__(16) short lAr[4 * 8192];    // 64KB
  const int lane = threadIdx.x & 63, wave = threadIdx.x >> 6;
  const int wm = wave >> 2, wn = wave & 3;         // per-wave out: 128 x 32
  int bx = blockIdx.x, by = blockIdx.y;
  {
    const int flat = by * 8 + bx;                  // gridDim.x == 8
    const int chunk = (int)(gridDim.x * gridDim.y) >> 3;
    const int fid = (flat & 7) * chunk + (flat >> 3);
    bx = fid & 7; by = fid >> 3;
  }
  const long bm = (long)by * 256;
  const int  bn = bx * 128;

  const short* Aqb = qb + bm * 1024;
  const short* Arb = rb + bm * 1024;
  constexpr int NS = 32;                           // K = 1024
  const int g0 = lane >> 4;
  const int arow = wm * 128 + (lane & 15);

  const char* aPq = (const char*)lAq + arow * 64 + (((g0 ^ (arow >> 1)) & 3) << 4);
  const char* aPr = (const char*)lAr + arow * 64 + (((g0 ^ (arow >> 1)) & 3) << 4);
  // frag-linear B bases: col-block cb = bn/16 + wn*2 + j, stride 16384 elems
  const long cb0 = (long)(bn / 16 + wn * 2) * 16384 + g0 * 128 + ((lane & 15) << 3);
  const short* qG = wqt + cb0;
  const short* kG = wkt + cb0;
  const short* vG = wvt + cb0;

  const int rw = lane >> 2;
  const int gg = (lane & 3) ^ ((rw >> 1) & 3);
  const short* Aqsrc = Aqb + (wave * 16 + rw) * 1024 + (gg << 3);
  const short* Arsrc = Arb + (wave * 16 + rw) * 1024 + (gg << 3);
  short* lAqd = lAq + wave * 16 * 32;
  short* lArd = lAr + wave * 16 * 32;

  auto stA = [&](int slot, int s) {                // Aq + Ar, 4 loads
    const int sc = s < NS ? s : NS - 1;            // tail: clamp SOURCE only
    const short* sq = Aqsrc + sc * 32;
    const short* sr = Arsrc + sc * 32;
    short* dq = lAqd + slot * 8192;
    short* dr = lArd + slot * 8192;
    __builtin_amdgcn_global_load_lds((const AS1 void*)sq,              (AS3 void*)dq,        16, 0, 0);
    __builtin_amdgcn_global_load_lds((const AS1 void*)(sq + 128*1024), (AS3 void*)(dq+4096), 16, 0, 0);
    __builtin_amdgcn_global_load_lds((const AS1 void*)sr,              (AS3 void*)dr,        16, 0, 0);
    __builtin_amdgcn_global_load_lds((const AS1 void*)(sr + 128*1024), (AS3 void*)(dr+4096), 16, 0, 0);
  };
  auto ldB = [&](bf16x8* dq, bf16x8* dk, bf16x8* dv, int s) {  // 6 loads
    const int sc = s < NS ? s : NS - 1;
    #pragma unroll
    for (int j = 0; j < 2; ++j) {
      dq[j] = *(const bf16x8*)(qG + (long)j * 16384 + sc * 512);
      dk[j] = *(const bf16x8*)(kG + (long)j * 16384 + sc * 512);
      dv[j] = *(const bf16x8*)(vG + (long)j * 16384 + sc * 512);
    }
  };

  // prologue: b0 slice 0 (6), A slices 0,1,2 (12); vmcnt(8) proves b0+A(0)
  bf16x8 bq0[2], bk0[2], bv0[2], bq1[2], bk1[2], bv1[2];
  ldB(bq0, bk0, bv0, 0);
  stA(0, 0); stA(1, 1); stA(2, 2);
  asm volatile("s_waitcnt vmcnt(8)" ::: "memory");
  __builtin_amdgcn_s_barrier();

  f32x4 acq[8][2] = {};
  f32x4 ack[8][2] = {};
  f32x4 acv[8][2] = {};

#define PHASEQ(SLOT, MH, BQ, BK, BV, STMT, DOVM)                            \
  {                                                                         \
    bf16x8 aq[4], ar[4];                                                    \
    _Pragma("unroll")                                                       \
    for (int i2 = 0; i2 < 4; ++i2) {                                        \
      aq[i2] = *(const bf16x8*)(aPq + (SLOT) * 16384 + (MH) * 4096 + i2 * 1024); \
      ar[i2] = *(const bf16x8*)(aPr + (SLOT) * 16384 + (MH) * 4096 + i2 * 1024); \
    }                                                                       \
    STMT;                                                                   \
    if (DOVM) asm volatile("s_waitcnt vmcnt(14)" ::: "memory");             \
    asm volatile("" ::: "memory");                                          \
    __builtin_amdgcn_s_barrier();                                           \
    __builtin_amdgcn_s_setprio(1);                                          \
    _Pragma("unroll")                                                       \
    for (int i2 = 0; i2 < 4; ++i2)                                          \
      _Pragma("unroll")                                                     \
      for (int j = 0; j < 2; ++j)                                           \
        acq[(MH) * 4 + i2][j] = __builtin_amdgcn_mfma_f32_16x16x32_bf16(    \
            aq[i2], BQ[j], acq[(MH) * 4 + i2][j], 0, 0, 0);                 \
    _Pragma("unroll")                                                       \
    for (int i2 = 0; i2 < 4; ++i2)                                          \
      _Pragma("unroll")                                                     \
      for (int j = 0; j < 2; ++j) {                                         \
        ack[(MH) * 4 + i2][j] = __builtin_amdgcn_mfma_f32_16x16x32_bf16(    \
            ar[i2], BK[j], ack[(MH) * 4 + i2][j], 0, 0, 0);                 \
        acv[(MH) * 4 + i2][j] = __builtin_amdgcn_mfma_f32_16x16x32_bf16(    \
            ar[i2], BV[j], acv[(MH) * 4 + i2][j], 0, 0, 0);                 \
      }                                                                     \
    __builtin_amdgcn_s_setprio(0);                                          \
    asm volatile("" ::: "memory");                                          \
    __builtin_amdgcn_s_barrier();                                           \
  }

  for (int s = 0; s < NS; s += 4) {
    PHASEQ(0, 0, bq0, bk0, bv0, { ldB(bq1, bk1, bv1, s + 1); stA(3, s + 3); }, false)
    PHASEQ(0, 1, bq0, bk0, bv0, {}, true)
    PHASEQ(1, 0, bq1, bk1, bv1, { ldB(bq0, bk0, bv0, s + 2); stA(0, s + 4); }, false)
    PHASEQ(1, 1, bq1, bk1, bv1, {}, true)
    PHASEQ(2, 0, bq0, bk0, bv0, { ldB(bq1, bk1, bv1, s + 3); stA(1, s + 5); }, false)
    PHASEQ(2, 1, bq0, bk0, bv0, {}, true)
    PHASEQ(3, 0, bq1, bk1, bv1, { ldB(bq0, bk0, bv0, s + 4); stA(2, s + 6); }, false)
    PHASEQ(3, 1, bq1, bk1, bv1, {}, true)
  }
#undef PHASEQ

  // epilogue: z = sigmoid(Qh * Kh / 16) * Vh, all from registers (R14-verified)
  #pragma unroll
  for (int i = 0; i < 8; ++i)
    #pragma unroll
    for (int j = 0; j < 2; ++j)
      #pragma unroll
      for (int r = 0; r < 4; ++r) {
        const int rl = wm * 128 + i * 16 + ((lane >> 4) << 2) + r;
        const int cl = wn * 32 + j * 16 + (lane & 15);
        const long gi = (bm + rl) * 1024 + bn + cl;
        const float x = acq[i][j][r] * ack[i][j][r] * 0.0625f;
        const float gate = 1.0f / (1.0f + __expf(-x));
        zb[gi] = f2b(gate * acv[i][j][r]);
      }
}

// ------------- fused MLP: ug = relu(z_h @ W1_h + b1) @ W2_h + b2 (R13) ---
__global__ __launch_bounds__(512) void gemm_mlp(
    const short* __restrict__ zb, const short* __restrict__ w1t,
    const short* __restrict__ w2t, const float* __restrict__ b1,
    const float* __restrict__ b2, short* __restrict__ ug)
{
  __shared__ __align__(16) char smem[163840];
  short* lA = (short*)smem;                        // pass1: 4 x 16KB
  short* lB = (short*)(smem + 65536);              // pass1: 4 x 16KB
  short* stash = (short*)smem;                     // h1: 128KB (after pass1)
  short* w2b = (short*)(smem + 131072);            // pass2 B: 2 x 16KB

  const int lane = threadIdx.x & 63, wave = threadIdx.x >> 6;
  const int wm = wave >> 2, wn = wave & 3;
  const long bm = (long)blockIdx.y * 256;
  const int head = blockIdx.z;

  const int g0 = lane >> 4;
  const int arow = wm * 128 + (lane & 15);
  const int bcol = wn * 64 + (lane & 15);
  const int rw = lane >> 2;
  const int gg = (lane & 3) ^ ((rw >> 1) & 3);

  // ---------- pass 1: h1 = relu(z_h @ W1_h + b1) ----------
  {
    const short* Ab = zb + bm * 1024 + head * 256;
    const short* Bb = w1t + head * 65536;
    const char* aP = (const char*)lA + arow * 64 + (((g0 ^ (arow >> 1)) & 3) << 4);
    const char* bP = (const char*)lB + bcol * 64 + (((g0 ^ (bcol >> 1)) & 3) << 4);
    const short* Asrc = Ab + (wave * 16 + rw) * 1024 + (gg << 3);
    const short* Bsrc = Bb + (wave * 16 + rw) * 256 + (gg << 3);
    short* lAd = lA + wave * 16 * 32;
    short* lBd = lB + wave * 16 * 32;

    auto stA = [&](int slot, int s) {
      const int sc = s < 8 ? s : 7;
      const short* src = Asrc + sc * 32;
      short* d = lAd + slot * 8192;
      __builtin_amdgcn_global_load_lds((const AS1 void*)src,              (AS3 void*)d,        16, 0, 0);
      __builtin_amdgcn_global_load_lds((const AS1 void*)(src + 128*1024), (AS3 void*)(d+4096), 16, 0, 0);
    };
    auto stB = [&](int slot, int s) {
      const int sc = s < 8 ? s : 7;
      const short* src = Bsrc + sc * 32;
      short* d = lBd + slot * 8192;
      __builtin_amdgcn_global_load_lds((const AS1 void*)src,              (AS3 void*)d,        16, 0, 0);
      __builtin_amdgcn_global_load_lds((const AS1 void*)(src + 128*256),  (AS3 void*)(d+4096), 16, 0, 0);
    };

    stA(0, 0); stB(0, 0);
    stA(1, 1); stB(1, 1);
    stA(2, 2); stB(2, 2);
    asm volatile("s_waitcnt vmcnt(8)" ::: "memory");
    __builtin_amdgcn_s_barrier();

    f32x4 acc[8][4] = {};
    bf16x8 b[4];

#define PHASE1(SLOT, MH, LOADB, STAGE_STMT, DOVM)                           \
    {                                                                       \
      if (LOADB) {                                                          \
        _Pragma("unroll")                                                   \
        for (int j = 0; j < 4; ++j)                                         \
          b[j] = *(const bf16x8*)(bP + (SLOT) * 16384 + j * 1024);          \
      }                                                                     \
      bf16x8 a[4];                                                          \
      _Pragma("unroll")                                                     \
      for (int i2 = 0; i2 < 4; ++i2)                                        \
        a[i2] = *(const bf16x8*)(aP + (SLOT) * 16384 + (MH) * 4096 + i2 * 1024); \
      STAGE_STMT;                                                           \
      if (DOVM) asm volatile("s_waitcnt vmcnt(8)" ::: "memory");            \
      asm volatile("" ::: "memory");                                        \
      __builtin_amdgcn_s_barrier();                                         \
      __builtin_amdgcn_s_setprio(1);                                        \
      _Pragma("unroll")                                                     \
      for (int i2 = 0; i2 < 4; ++i2)                                        \
        _Pragma("unroll")                                                   \
        for (int j = 0; j < 4; ++j)                                         \
          acc[(MH) * 4 + i2][j] = __builtin_amdgcn_mfma_f32_16x16x32_bf16(  \
              a[i2], b[j], acc[(MH) * 4 + i2][j], 0, 0, 0);                 \
      __builtin_amdgcn_s_setprio(0);                                        \
      asm volatile("" ::: "memory");                                        \
      __builtin_amdgcn_s_barrier();                                         \
    }

    for (int s = 0; s < 8; s += 4) {
      PHASE1(0, 0, true,  stA(3, s + 3), false) PHASE1(0, 1, false, stB(3, s + 3), true)
      PHASE1(1, 0, true,  stA(0, s + 4), false) PHASE1(1, 1, false, stB(0, s + 4), true)
      PHASE1(2, 0, true,  stA(1, s + 5), false) PHASE1(2, 1, false, stB(1, s + 5), true)
      PHASE1(3, 0, true,  stA(2, s + 6), false) PHASE1(3, 1, false, stB(2, s + 6), true)
    }
#undef PHASE1

    __syncthreads();     // all pass-1 LDS reads done before stash overwrite
    #pragma unroll
    for (int i = 0; i < 8; ++i)
      #pragma unroll
      for (int j = 0; j < 4; ++j)
        #pragma unroll
        for (int r = 0; r < 4; ++r) {
          const int rl = wm * 128 + i * 16 + ((lane >> 4) << 2) + r;
          const int cl = wn * 64 + j * 16 + (lane & 15);
          float v = acc[i][j][r] + b1[head * 256 + cl];
          v = v > 0.0f ? v : 0.0f;
          stash[rl * 256 + ((((cl >> 3) ^ rl) & 31) << 3) + (cl & 7)] = f2b(v);
        }
    __syncthreads();     // stash complete before pass-2 reads
  }

  // ---------- pass 2: ug = h1 @ W2_h + b2 ----------
  {
    const short* Wb = w2t + head * 65536;
    const short* Bsrc2 = Wb + (wave * 16 + rw) * 256 + (gg << 3);
    short* lBd2 = w2b + wave * 16 * 32;
    const char* b2P = (const char*)w2b + bcol * 64 + (((g0 ^ (bcol >> 1)) & 3) << 4);

    auto stW = [&](int slot, int s) {
      const int sc = s < 8 ? s : 7;
      const short* src = Bsrc2 + sc * 32;
      short* d = lBd2 + slot * 8192;
      __builtin_amdgcn_global_load_lds((const AS1 void*)src,             (AS3 void*)d,        16, 0, 0);
      __builtin_amdgcn_global_load_lds((const AS1 void*)(src + 128*256), (AS3 void*)(d+4096), 16, 0, 0);
    };

    stW(0, 0);
    asm volatile("s_waitcnt vmcnt(0)" ::: "memory");
    __builtin_amdgcn_s_barrier();

    f32x4 acc2[8][4] = {};
    bf16x8 br[4];

    for (int s = 0; s < 8; ++s) {
      const int sl = s & 1;
      const int ks = s * 4 + g0;       // 16B k-slot index in stash

#define PHASE2(MH, LOADB, STAGE_STMT, DOVM)                                 \
      {                                                                     \
        if (LOADB) {                                                        \
          _Pragma("unroll")                                                 \
          for (int j = 0; j < 4; ++j)                                       \
            br[j] = *(const bf16x8*)(b2P + sl * 16384 + j * 1024);          \
        }                                                                   \
        bf16x8 a[4];                                                        \
        _Pragma("unroll")                                                   \
        for (int i2 = 0; i2 < 4; ++i2) {                                    \
          const int row = arow + (MH) * 64 + i2 * 16;                       \
          a[i2] = *(const bf16x8*)(stash + row * 256 + (((ks ^ row) & 31) << 3)); \
        }                                                                   \
        STAGE_STMT;                                                         \
        if (DOVM) asm volatile("s_waitcnt vmcnt(0)" ::: "memory");          \
        asm volatile("" ::: "memory");                                      \
        __builtin_amdgcn_s_barrier();                                       \
        __builtin_amdgcn_s_setprio(1);                                      \
        _Pragma("unroll")                                                   \
        for (int i2 = 0; i2 < 4; ++i2)                                      \
          _Pragma("unroll")                                                 \
          for (int j = 0; j < 4; ++j)                                       \
            acc2[(MH) * 4 + i2][j] = __builtin_amdgcn_mfma_f32_16x16x32_bf16( \
                a[i2], br[j], acc2[(MH) * 4 + i2][j], 0, 0, 0);             \
        __builtin_amdgcn_s_setprio(0);                                      \
        asm volatile("" ::: "memory");                                      \
        __builtin_amdgcn_s_barrier();                                       \
      }

      PHASE2(0, true,  stW(sl ^ 1, s + 1), false)
      PHASE2(1, false, {}, true)
#undef PHASE2
    }

    #pragma unroll
    for (int i = 0; i < 8; ++i)
      #pragma unroll
      for (int j = 0; j < 4; ++j)
        #pragma unroll
        for (int r = 0; r < 4; ++r) {
          const int rl = wm * 128 + i * 16 + ((lane >> 4) << 2) + r;
          const int cl = wn * 64 + j * 16 + (lane & 15);
          const float v = acc2[i][j][r] + b2[head * 256 + cl];
          ug[(bm + rl) * 1024 + head * 256 + cl] = f2b(v);
        }
  }
}

extern "C" void kernel_launch(void* const* d_in, const int* in_sizes, int n_in,
                              void* d_out, int out_size, void* d_ws, size_t ws_size,
                              hipStream_t stream) {
  const float* q   = (const float*)d_in[0];
  const float* rep = (const float*)d_in[1];
  const float* Wq  = (const float*)d_in[2];
  const float* Wk  = (const float*)d_in[3];
  const float* Wv  = (const float*)d_in[4];
  const float* W1  = (const float*)d_in[5];
  const float* b1  = (const float*)d_in[6];
  const float* W2  = (const float*)d_in[7];
  const float* b2  = (const float*)d_in[8];
  const float* Ws  = (const float*)d_in[9];
  float* out = (float*)d_out;

  const long NE = 67108864L;   // 65536 * 1024
  char* ws = (char*)d_ws;
  // 4 x 128 MiB slots:
  //   s0: qb (cvt..F)   s1: rb (cvt..F)
  //   s2: ug (mlp..F)   s3: zb (g123..mlp)
  short* qb  = (short*)(ws);
  short* rb  = (short*)(ws + NE * 2);
  short* ugb = (short*)(ws + NE * 4);
  short* zb  = (short*)(ws + NE * 6);
  char*  wp  = ws + NE * 8;
  short* wqt = (short*)(wp);                 // 2 MiB each
  short* wkt = (short*)(wp + 2097152);
  short* wvt = (short*)(wp + 4194304);
  short* wst = (short*)(wp + 6291456);
  short* w1t = (short*)(wp + 8388608);       // 512 KiB
  short* w2t = (short*)(wp + 8912896);       // 512 KiB

  cvt_bf16_2<<<dim3(2048, 1, 2), 256, 0, stream>>>(q, rep, qb, rb, NE);
  prep_weights<<<dim3(32, 32, 12), dim3(32, 8), 0, stream>>>(
      Wq, Wk, Wv, W1, W2, Ws, wqt, wkt, wvt, w1t, w2t, wst);

  // g123: z = sigmoid((q@Wq) * (rep@Wk) / 16) * (rep@Wv)  -> zb
  gemm_g123<<<dim3(8, 256), 512, 0, stream>>>(qb, rb, wqt, wkt, wvt, zb);
  // fused MLP: ug = relu(z@W1+b1)@W2+b2  (h1 never leaves LDS)
  gemm_mlp<<<dim3(1, 256, 4), 512, 0, stream>>>(zb, w1t, w2t, b1, b2, ugb);
  // F: out = (q - rep) + ug @ Ws   [A-only LDS, B global, f32 residual]
  gemm_bt<1024, true><<<dim3(4, 256), 512, 0, stream>>>(
      ugb, wst, out, qb, rb);
}

// Round 18
// 1003.324 us; speedup vs baseline: 3.2024x; 3.2024x over previous
//
#include <hip/hip_runtime.h>
#include <hip/hip_bf16.h>

// TreeHopNode: h = q - rep + (per-head MLP(sigmoid(Qh*Kh/16)*Vh)) @ Ws
// N=65536, E=1024, H=4, G=256, MLP=256. bf16 MFMA 16x16x32, f32 accum.
//
// R18 = R13 RESTORED (best verified: 1001us, absmax 0.03125).
// Ledger of 17 rounds: schedule micro-variants x5 null (31% MfmaUtil
// plateau is the 2-barrier lockstep structure's fixed cost, m233);
// occupancy unreachable (register footprint ~224 locks 1 block/CU);
// acc[8][8] register blocking spills (R15); G1+G23 triple fusion spills
// or needs hot gates (R14/R17). All wins were WORK-REMOVAL:
//   R6  G2+G3 fusion (dual-acc, kills gate round-trip)      -69us
//   R13 MLP fusion (h1 lives in LDS, kills 256MB round-trip) -45us
//   R6  bf16 residual reads in F                             -30us
// Pipeline: cvt -> prep -> G1(gemm_bf16) -> g23 -> mlp -> F(gemm_bf16).

typedef __attribute__((ext_vector_type(8))) short bf16x8;
typedef __attribute__((ext_vector_type(4))) float f32x4;
typedef __attribute__((ext_vector_type(4))) short short4v;

#define AS1 __attribute__((address_space(1)))
#define AS3 __attribute__((address_space(3)))

static __device__ __forceinline__ short f2b(float x) {
  __hip_bfloat16 h = __float2bfloat16(x);
  return __builtin_bit_cast(short, h);
}
static __device__ __forceinline__ float b2f(short s) {
  unsigned u = ((unsigned)(unsigned short)s) << 16;
  return __builtin_bit_cast(float, u);
}

// ---------------- convert f32 -> bf16 (both inputs, one launch) ----------
__global__ void cvt_bf16_2(const float* __restrict__ q, const float* __restrict__ rep,
                           short* __restrict__ qb, short* __restrict__ rb, long n) {
  const float* __restrict__ in = blockIdx.z ? rep : q;
  short* __restrict__ out = blockIdx.z ? rb : qb;
  long i = ((long)blockIdx.x * blockDim.x + threadIdx.x) * 4;
  const long stride = (long)gridDim.x * blockDim.x * 4;
  for (; i < n; i += stride) {
    float4 v = *(const float4*)(in + i);
    short4v o = { f2b(v.x), f2b(v.y), f2b(v.z), f2b(v.w) };
    *(short4v*)(out + i) = o;
  }
}

// ---------------- transpose + convert weights ----------------
__global__ void prep_weights(
    const float* __restrict__ Wq, const float* __restrict__ Wk, const float* __restrict__ Wv,
    const float* __restrict__ W1, const float* __restrict__ W2, const float* __restrict__ Ws,
    short* __restrict__ wqt, short* __restrict__ wkt, short* __restrict__ wvt,
    short* __restrict__ w1t, short* __restrict__ w2t, short* __restrict__ wst)
{
  const int job = blockIdx.z;
  const float* src; short* dst; int R, C;
  if (job < 3)       { src = (job==0)?Wq:((job==1)?Wk:Wv); dst = (job==0)?wqt:((job==1)?wkt:wvt); R = 1024; C = 1024; }
  else if (job == 3) { src = Ws; dst = wst; R = 1024; C = 1024; }
  else if (job < 8)  { int h = job-4; src = W1 + h*65536; dst = w1t + h*65536; R = 256; C = 256; }
  else               { int h = job-8; src = W2 + h*65536; dst = w2t + h*65536; R = 256; C = 256; }
  const int c0 = blockIdx.x * 32, r0 = blockIdx.y * 32;
  if (c0 >= C || r0 >= R) return;
  __shared__ float t[32][33];
  for (int i = threadIdx.y; i < 32; i += 8)
    t[i][threadIdx.x] = src[(long)(r0 + i) * C + c0 + threadIdx.x];
  __syncthreads();
  for (int i = threadIdx.y; i < 32; i += 8)
    dst[(long)(c0 + i) * R + r0 + threadIdx.x] = f2b(t[threadIdx.x][i]);
}

// ---------------- 256x256-tile bf16 GEMM, 4-slot pipeline ----------------
template <int KDIM, int LDA, int LDB, bool RELU, bool BIAS, bool RESID, bool SWZ>
__global__ __launch_bounds__(512, 2) void gemm_bf16(
    const short* __restrict__ A, long zsa,
    const short* __restrict__ Bt, long zsb,
    void* __restrict__ outv, long ldc, long zsc,
    const float* __restrict__ bias, long zsbias,
    const short* __restrict__ qres, const short* __restrict__ rres)
{
  __shared__ __align__(16) short lA[4 * 8192];     // 4 slots of [256][32]
  __shared__ __align__(16) short lB[4 * 8192];
  const int lane = threadIdx.x & 63, wave = threadIdx.x >> 6;
  const int wm = wave >> 2, wn = wave & 3;         // 2M x 4N wave grid
  int bx = blockIdx.x, by = blockIdx.y;
  if (SWZ) {
    const int nbx = gridDim.x;
    const int flat = by * nbx + bx;
    const int chunk = (int)(gridDim.x * gridDim.y) >> 3;
    const int fid = (flat & 7) * chunk + (flat >> 3);
    bx = fid % nbx; by = fid / nbx;
  }
  const long bm = (long)by * 256;
  const int  bn = bx * 256;
  const int  zi = blockIdx.z;

  const short* Ab = A + (long)zi * zsa + bm * LDA;
  const short* Bb = Bt + (long)zi * zsb + (long)bn * LDB;
  constexpr int NS = KDIM / 32;                    // k-slices (32 wide)
  const int g0 = lane >> 4;
  const int arow = wm * 128 + (lane & 15);
  const int bcol = wn * 64 + (lane & 15);

  const char* aP = (const char*)lA + arow * 64 + (((g0 ^ (arow >> 1)) & 3) << 4);
  const char* bP = (const char*)lB + bcol * 64 + (((g0 ^ (bcol >> 1)) & 3) << 4);

  const int rw = lane >> 2;
  const int gg = (lane & 3) ^ ((rw >> 1) & 3);
  const short* Asrc = Ab + (wave * 16 + rw) * LDA + (gg << 3);
  const short* Bsrc = Bb + (wave * 16 + rw) * LDB + (gg << 3);
  short* lAd = lA + wave * 16 * 32;
  short* lBd = lB + wave * 16 * 32;

  auto stA = [&](int slot, int s) {
    const int sc = s < NS ? s : NS - 1;            // tail: clamp SOURCE only
    const short* src = Asrc + sc * 32;
    short* d = lAd + slot * 8192;
    __builtin_amdgcn_global_load_lds((const AS1 void*)src,              (AS3 void*)d,        16, 0, 0);
    __builtin_amdgcn_global_load_lds((const AS1 void*)(src + 128*LDA),  (AS3 void*)(d+4096), 16, 0, 0);
  };
  auto stB = [&](int slot, int s) {
    const int sc = s < NS ? s : NS - 1;
    const short* src = Bsrc + sc * 32;
    short* d = lBd + slot * 8192;
    __builtin_amdgcn_global_load_lds((const AS1 void*)src,              (AS3 void*)d,        16, 0, 0);
    __builtin_amdgcn_global_load_lds((const AS1 void*)(src + 128*LDB),  (AS3 void*)(d+4096), 16, 0, 0);
  };

  stA(0, 0); stB(0, 0);
  stA(1, 1); stB(1, 1);
  stA(2, 2); stB(2, 2);
  asm volatile("s_waitcnt vmcnt(8)" ::: "memory");
  __builtin_amdgcn_s_barrier();

  f32x4 acc[8][4] = {};
  bf16x8 b[4];

#define PHASE(SLOT, MH, LOADB, STAGE_STMT, DOVM)                            \
  {                                                                         \
    if (LOADB) {                                                            \
      _Pragma("unroll")                                                     \
      for (int j = 0; j < 4; ++j)                                           \
        b[j] = *(const bf16x8*)(bP + (SLOT) * 16384 + j * 1024);            \
    }                                                                       \
    bf16x8 a[4];                                                            \
    _Pragma("unroll")                                                       \
    for (int i2 = 0; i2 < 4; ++i2)                                          \
      a[i2] = *(const bf16x8*)(aP + (SLOT) * 16384 + (MH) * 4096 + i2 * 1024); \
    STAGE_STMT;                                                             \
    if (DOVM) asm volatile("s_waitcnt vmcnt(8)" ::: "memory");              \
    asm volatile("" ::: "memory");                                          \
    __builtin_amdgcn_s_barrier();                                           \
    __builtin_amdgcn_s_setprio(1);                                          \
    _Pragma("unroll")                                                       \
    for (int i2 = 0; i2 < 4; ++i2)                                          \
      _Pragma("unroll")                                                     \
      for (int j = 0; j < 4; ++j)                                           \
        acc[(MH) * 4 + i2][j] = __builtin_amdgcn_mfma_f32_16x16x32_bf16(    \
            a[i2], b[j], acc[(MH) * 4 + i2][j], 0, 0, 0);                   \
    __builtin_amdgcn_s_setprio(0);                                          \
    asm volatile("" ::: "memory");                                          \
    __builtin_amdgcn_s_barrier();                                           \
  }

  for (int s = 0; s < NS; s += 4) {
    PHASE(0, 0, true,  stA(3, s + 3), false) PHASE(0, 1, false, stB(3, s + 3), true)
    PHASE(1, 0, true,  stA(0, s + 4), false) PHASE(1, 1, false, stB(0, s + 4), true)
    PHASE(2, 0, true,  stA(1, s + 5), false) PHASE(2, 1, false, stB(1, s + 5), true)
    PHASE(3, 0, true,  stA(2, s + 6), false) PHASE(3, 1, false, stB(2, s + 6), true)
  }
#undef PHASE

  // epilogue; C/D layout: col=lane&15, row=(lane>>4)*4+reg (m89)
  #pragma unroll
  for (int i = 0; i < 8; ++i)
    #pragma unroll
    for (int j = 0; j < 4; ++j)
      #pragma unroll
      for (int r = 0; r < 4; ++r) {
        const int rl = wm * 128 + i * 16 + ((lane >> 4) << 2) + r;
        const int cl = wn * 64 + j * 16 + (lane & 15);
        float v = acc[i][j][r];
        if (BIAS) v += bias[(long)zi * zsbias + bn + cl];
        if (RELU) v = v > 0.0f ? v : 0.0f;
        const long row = bm + rl;
        const long gi = (long)zi * zsc + row * ldc + bn + cl;
        if (RESID) {
          ((float*)outv)[gi] = b2f(qres[gi]) - b2f(rres[gi]) + v;
        } else {
          ((short*)outv)[gi] = f2b(v);
        }
      }
}

// ------------- merged G2+G3: z = sigmoid(Qh*Kh/16) * Vh -----------------
__global__ __launch_bounds__(512, 2) void gemm_g23(
    const short* __restrict__ rb, const short* __restrict__ wkt,
    const short* __restrict__ wvt, const short* __restrict__ gh,
    short* __restrict__ zb)
{
  __shared__ __align__(16) short lA[4 * 8192];
  __shared__ __align__(16) short lK[4 * 4096];
  __shared__ __align__(16) short lV[4 * 4096];
  const int lane = threadIdx.x & 63, wave = threadIdx.x >> 6;
  const int wm = wave >> 2, wn = wave & 3;
  int bx = blockIdx.x, by = blockIdx.y;
  {
    const int flat = by * 8 + bx;
    const int chunk = (int)(gridDim.x * gridDim.y) >> 3;
    const int fid = (flat & 7) * chunk + (flat >> 3);
    bx = fid & 7; by = fid >> 3;
  }
  const long bm = (long)by * 256;
  const int  bn = bx * 128;

  const short* Ab = rb + bm * 1024;
  const short* Kb = wkt + (long)bn * 1024;
  const short* Vb = wvt + (long)bn * 1024;
  constexpr int NS = 32;
  const int g0 = lane >> 4;
  const int arow = wm * 128 + (lane & 15);
  const int bcol = wn * 32 + (lane & 15);

  const char* aP = (const char*)lA + arow * 64 + (((g0 ^ (arow >> 1)) & 3) << 4);
  const char* kP = (const char*)lK + bcol * 64 + (((g0 ^ (bcol >> 1)) & 3) << 4);
  const char* vP = (const char*)lV + bcol * 64 + (((g0 ^ (bcol >> 1)) & 3) << 4);

  const int rw = lane >> 2;
  const int gg = (lane & 3) ^ ((rw >> 1) & 3);
  const short* Asrc = Ab + (wave * 16 + rw) * 1024 + (gg << 3);
  const short* Ksrc = Kb + (wave * 16 + rw) * 1024 + (gg << 3);
  const short* Vsrc = Vb + (wave * 16 + rw) * 1024 + (gg << 3);
  short* lAd = lA + wave * 16 * 32;
  short* lKd = lK + wave * 16 * 32;
  short* lVd = lV + wave * 16 * 32;

  auto stA = [&](int slot, int s) {
    const int sc = s < NS ? s : NS - 1;
    const short* src = Asrc + sc * 32;
    short* d = lAd + slot * 8192;
    __builtin_amdgcn_global_load_lds((const AS1 void*)src,               (AS3 void*)d,        16, 0, 0);
    __builtin_amdgcn_global_load_lds((const AS1 void*)(src + 128*1024),  (AS3 void*)(d+4096), 16, 0, 0);
  };
  auto stKV = [&](int slot, int s) {
    const int sc = s < NS ? s : NS - 1;
    __builtin_amdgcn_global_load_lds((const AS1 void*)(Ksrc + sc * 32), (AS3 void*)(lKd + slot * 4096), 16, 0, 0);
    __builtin_amdgcn_global_load_lds((const AS1 void*)(Vsrc + sc * 32), (AS3 void*)(lVd + slot * 4096), 16, 0, 0);
  };

  stA(0, 0); stKV(0, 0);
  stA(1, 1); stKV(1, 1);
  stA(2, 2); stKV(2, 2);
  asm volatile("s_waitcnt vmcnt(8)" ::: "memory");
  __builtin_amdgcn_s_barrier();

  f32x4 ack[8][2] = {};
  f32x4 acv[8][2] = {};
  bf16x8 bk[2], bv[2];

#define PHASEG(SLOT, MH, LOADB, STAGE_STMT, DOVM)                           \
  {                                                                         \
    if (LOADB) {                                                            \
      _Pragma("unroll")                                                     \
      for (int j = 0; j < 2; ++j) {                                         \
        bk[j] = *(const bf16x8*)(kP + (SLOT) * 8192 + j * 1024);            \
        bv[j] = *(const bf16x8*)(vP + (SLOT) * 8192 + j * 1024);            \
      }                                                                     \
    }                                                                       \
    bf16x8 a[4];                                                            \
    _Pragma("unroll")                                                       \
    for (int i2 = 0; i2 < 4; ++i2)                                          \
      a[i2] = *(const bf16x8*)(aP + (SLOT) * 16384 + (MH) * 4096 + i2 * 1024); \
    STAGE_STMT;                                                             \
    if (DOVM) asm volatile("s_waitcnt vmcnt(8)" ::: "memory");              \
    asm volatile("" ::: "memory");                                          \
    __builtin_amdgcn_s_barrier();                                           \
    __builtin_amdgcn_s_setprio(1);                                          \
    _Pragma("unroll")                                                       \
    for (int i2 = 0; i2 < 4; ++i2)                                          \
      _Pragma("unroll")                                                     \
      for (int j = 0; j < 2; ++j) {                                         \
        ack[(MH) * 4 + i2][j] = __builtin_amdgcn_mfma_f32_16x16x32_bf16(    \
            a[i2], bk[j], ack[(MH) * 4 + i2][j], 0, 0, 0);                  \
        acv[(MH) * 4 + i2][j] = __builtin_amdgcn_mfma_f32_16x16x32_bf16(    \
            a[i2], bv[j], acv[(MH) * 4 + i2][j], 0, 0, 0);                  \
      }                                                                     \
    __builtin_amdgcn_s_setprio(0);                                          \
    asm volatile("" ::: "memory");                                          \
    __builtin_amdgcn_s_barrier();                                           \
  }

  for (int s = 0; s < NS; s += 4) {
    PHASEG(0, 0, true,  stA(3, s + 3), false) PHASEG(0, 1, false, stKV(3, s + 3), true)
    PHASEG(1, 0, true,  stA(0, s + 4), false) PHASEG(1, 1, false, stKV(0, s + 4), true)
    PHASEG(2, 0, true,  stA(1, s + 5), false) PHASEG(2, 1, false, stKV(1, s + 5), true)
    PHASEG(3, 0, true,  stA(2, s + 6), false) PHASEG(3, 1, false, stKV(2, s + 6), true)
  }
#undef PHASEG

  #pragma unroll
  for (int i = 0; i < 8; ++i)
    #pragma unroll
    for (int j = 0; j < 2; ++j)
      #pragma unroll
      for (int r = 0; r < 4; ++r) {
        const int rl = wm * 128 + i * 16 + ((lane >> 4) << 2) + r;
        const int cl = wn * 32 + j * 16 + (lane & 15);
        const long gi = (bm + rl) * 1024 + bn + cl;
        const float x = b2f(gh[gi]) * ack[i][j][r] * 0.0625f;
        const float gate = 1.0f / (1.0f + __expf(-x));
        zb[gi] = f2b(gate * acv[i][j][r]);
      }
}

// ------------- fused MLP: ug = relu(z_h @ W1_h + b1) @ W2_h + b2 --------
__global__ __launch_bounds__(512) void gemm_mlp(
    const short* __restrict__ zb, const short* __restrict__ w1t,
    const short* __restrict__ w2t, const float* __restrict__ b1,
    const float* __restrict__ b2, short* __restrict__ ug)
{
  __shared__ __align__(16) char smem[163840];
  short* lA = (short*)smem;                        // pass1: 4 x 16KB
  short* lB = (short*)(smem + 65536);              // pass1: 4 x 16KB
  short* stash = (short*)smem;                     // h1: 128KB (after pass1)
  short* w2b = (short*)(smem + 131072);            // pass2 B: 2 x 16KB

  const int lane = threadIdx.x & 63, wave = threadIdx.x >> 6;
  const int wm = wave >> 2, wn = wave & 3;
  const long bm = (long)blockIdx.y * 256;
  const int head = blockIdx.z;

  const int g0 = lane >> 4;
  const int arow = wm * 128 + (lane & 15);
  const int bcol = wn * 64 + (lane & 15);
  const int rw = lane >> 2;
  const int gg = (lane & 3) ^ ((rw >> 1) & 3);

  // ---------- pass 1: h1 = relu(z_h @ W1_h + b1) ----------
  {
    const short* Ab = zb + bm * 1024 + head * 256;
    const short* Bb = w1t + head * 65536;
    const char* aP = (const char*)lA + arow * 64 + (((g0 ^ (arow >> 1)) & 3) << 4);
    const char* bP = (const char*)lB + bcol * 64 + (((g0 ^ (bcol >> 1)) & 3) << 4);
    const short* Asrc = Ab + (wave * 16 + rw) * 1024 + (gg << 3);
    const short* Bsrc = Bb + (wave * 16 + rw) * 256 + (gg << 3);
    short* lAd = lA + wave * 16 * 32;
    short* lBd = lB + wave * 16 * 32;

    auto stA = [&](int slot, int s) {
      const int sc = s < 8 ? s : 7;
      const short* src = Asrc + sc * 32;
      short* d = lAd + slot * 8192;
      __builtin_amdgcn_global_load_lds((const AS1 void*)src,              (AS3 void*)d,        16, 0, 0);
      __builtin_amdgcn_global_load_lds((const AS1 void*)(src + 128*1024), (AS3 void*)(d+4096), 16, 0, 0);
    };
    auto stB = [&](int slot, int s) {
      const int sc = s < 8 ? s : 7;
      const short* src = Bsrc + sc * 32;
      short* d = lBd + slot * 8192;
      __builtin_amdgcn_global_load_lds((const AS1 void*)src,              (AS3 void*)d,        16, 0, 0);
      __builtin_amdgcn_global_load_lds((const AS1 void*)(src + 128*256),  (AS3 void*)(d+4096), 16, 0, 0);
    };

    stA(0, 0); stB(0, 0);
    stA(1, 1); stB(1, 1);
    stA(2, 2); stB(2, 2);
    asm volatile("s_waitcnt vmcnt(8)" ::: "memory");
    __builtin_amdgcn_s_barrier();

    f32x4 acc[8][4] = {};
    bf16x8 b[4];

#define PHASE1(SLOT, MH, LOADB, STAGE_STMT, DOVM)                           \
    {                                                                       \
      if (LOADB) {                                                          \
        _Pragma("unroll")                                                   \
        for (int j = 0; j < 4; ++j)                                         \
          b[j] = *(const bf16x8*)(bP + (SLOT) * 16384 + j * 1024);          \
      }                                                                     \
      bf16x8 a[4];                                                          \
      _Pragma("unroll")                                                     \
      for (int i2 = 0; i2 < 4; ++i2)                                        \
        a[i2] = *(const bf16x8*)(aP + (SLOT) * 16384 + (MH) * 4096 + i2 * 1024); \
      STAGE_STMT;                                                           \
      if (DOVM) asm volatile("s_waitcnt vmcnt(8)" ::: "memory");            \
      asm volatile("" ::: "memory");                                        \
      __builtin_amdgcn_s_barrier();                                         \
      __builtin_amdgcn_s_setprio(1);                                        \
      _Pragma("unroll")                                                     \
      for (int i2 = 0; i2 < 4; ++i2)                                        \
        _Pragma("unroll")                                                   \
        for (int j = 0; j < 4; ++j)                                         \
          acc[(MH) * 4 + i2][j] = __builtin_amdgcn_mfma_f32_16x16x32_bf16(  \
              a[i2], b[j], acc[(MH) * 4 + i2][j], 0, 0, 0);                 \
      __builtin_amdgcn_s_setprio(0);                                        \
      asm volatile("" ::: "memory");                                        \
      __builtin_amdgcn_s_barrier();                                         \
    }

    for (int s = 0; s < 8; s += 4) {
      PHASE1(0, 0, true,  stA(3, s + 3), false) PHASE1(0, 1, false, stB(3, s + 3), true)
      PHASE1(1, 0, true,  stA(0, s + 4), false) PHASE1(1, 1, false, stB(0, s + 4), true)
      PHASE1(2, 0, true,  stA(1, s + 5), false) PHASE1(2, 1, false, stB(1, s + 5), true)
      PHASE1(3, 0, true,  stA(2, s + 6), false) PHASE1(3, 1, false, stB(2, s + 6), true)
    }
#undef PHASE1

    __syncthreads();     // all pass-1 LDS reads done before stash overwrite
    #pragma unroll
    for (int i = 0; i < 8; ++i)
      #pragma unroll
      for (int j = 0; j < 4; ++j)
        #pragma unroll
        for (int r = 0; r < 4; ++r) {
          const int rl = wm * 128 + i * 16 + ((lane >> 4) << 2) + r;
          const int cl = wn * 64 + j * 16 + (lane & 15);
          float v = acc[i][j][r] + b1[head * 256 + cl];
          v = v > 0.0f ? v : 0.0f;
          stash[rl * 256 + ((((cl >> 3) ^ rl) & 31) << 3) + (cl & 7)] = f2b(v);
        }
    __syncthreads();     // stash complete before pass-2 reads
  }

  // ---------- pass 2: ug = h1 @ W2_h + b2 ----------
  {
    const short* Wb = w2t + head * 65536;
    const short* Bsrc2 = Wb + (wave * 16 + rw) * 256 + (gg << 3);
    short* lBd2 = w2b + wave * 16 * 32;
    const char* b2P = (const char*)w2b + bcol * 64 + (((g0 ^ (bcol >> 1)) & 3) << 4);

    auto stW = [&](int slot, int s) {
      const int sc = s < 8 ? s : 7;
      const short* src = Bsrc2 + sc * 32;
      short* d = lBd2 + slot * 8192;
      __builtin_amdgcn_global_load_lds((const AS1 void*)src,             (AS3 void*)d,        16, 0, 0);
      __builtin_amdgcn_global_load_lds((const AS1 void*)(src + 128*256), (AS3 void*)(d+4096), 16, 0, 0);
    };

    stW(0, 0);
    asm volatile("s_waitcnt vmcnt(0)" ::: "memory");
    __builtin_amdgcn_s_barrier();

    f32x4 acc2[8][4] = {};
    bf16x8 br[4];

    for (int s = 0; s < 8; ++s) {
      const int sl = s & 1;
      const int ks = s * 4 + g0;       // 16B k-slot index in stash

#define PHASE2(MH, LOADB, STAGE_STMT, DOVM)                                 \
      {                                                                     \
        if (LOADB) {                                                        \
          _Pragma("unroll")                                                 \
          for (int j = 0; j < 4; ++j)                                       \
            br[j] = *(const bf16x8*)(b2P + sl * 16384 + j * 1024);          \
        }                                                                   \
        bf16x8 a[4];                                                        \
        _Pragma("unroll")                                                   \
        for (int i2 = 0; i2 < 4; ++i2) {                                    \
          const int row = arow + (MH) * 64 + i2 * 16;                       \
          a[i2] = *(const bf16x8*)(stash + row * 256 + (((ks ^ row) & 31) << 3)); \
        }                                                                   \
        STAGE_STMT;                                                         \
        if (DOVM) asm volatile("s_waitcnt vmcnt(0)" ::: "memory");          \
        asm volatile("" ::: "memory");                                      \
        __builtin_amdgcn_s_barrier();                                       \
        __builtin_amdgcn_s_setprio(1);                                      \
        _Pragma("unroll")                                                   \
        for (int i2 = 0; i2 < 4; ++i2)                                      \
          _Pragma("unroll")                                                 \
          for (int j = 0; j < 4; ++j)                                       \
            acc2[(MH) * 4 + i2][j] = __builtin_amdgcn_mfma_f32_16x16x32_bf16( \
                a[i2], br[j], acc2[(MH) * 4 + i2][j], 0, 0, 0);             \
        __builtin_amdgcn_s_setprio(0);                                      \
        asm volatile("" ::: "memory");                                      \
        __builtin_amdgcn_s_barrier();                                       \
      }

      PHASE2(0, true,  stW(sl ^ 1, s + 1), false)
      PHASE2(1, false, {}, true)
#undef PHASE2
    }

    #pragma unroll
    for (int i = 0; i < 8; ++i)
      #pragma unroll
      for (int j = 0; j < 4; ++j)
        #pragma unroll
        for (int r = 0; r < 4; ++r) {
          const int rl = wm * 128 + i * 16 + ((lane >> 4) << 2) + r;
          const int cl = wn * 64 + j * 16 + (lane & 15);
          const float v = acc2[i][j][r] + b2[head * 256 + cl];
          ug[(bm + rl) * 1024 + head * 256 + cl] = f2b(v);
        }
  }
}

extern "C" void kernel_launch(void* const* d_in, const int* in_sizes, int n_in,
                              void* d_out, int out_size, void* d_ws, size_t ws_size,
                              hipStream_t stream) {
  const float* q   = (const float*)d_in[0];
  const float* rep = (const float*)d_in[1];
  const float* Wq  = (const float*)d_in[2];
  const float* Wk  = (const float*)d_in[3];
  const float* Wv  = (const float*)d_in[4];
  const float* W1  = (const float*)d_in[5];
  const float* b1  = (const float*)d_in[6];
  const float* W2  = (const float*)d_in[7];
  const float* b2  = (const float*)d_in[8];
  const float* Ws  = (const float*)d_in[9];
  float* out = (float*)d_out;

  const long NE = 67108864L;   // 65536 * 1024
  char* ws = (char*)d_ws;
  // 4 x 128 MiB slots:
  //   s0: qb (cvt..F)   s1: rb (cvt..F)
  //   s2: gh (G1..g23) -> ug (mlp..F)
  //   s3: zb (g23..mlp)
  short* qb  = (short*)(ws);
  short* rb  = (short*)(ws + NE * 2);
  short* gh  = (short*)(ws + NE * 4);
  short* zb  = (short*)(ws + NE * 6);
  short* ugb = gh;
  char*  wp  = ws + NE * 8;
  short* wqt = (short*)(wp);                 // 2 MiB each
  short* wkt = (short*)(wp + 2097152);
  short* wvt = (short*)(wp + 4194304);
  short* wst = (short*)(wp + 6291456);
  short* w1t = (short*)(wp + 8388608);       // 512 KiB
  short* w2t = (short*)(wp + 8912896);       // 512 KiB

  cvt_bf16_2<<<dim3(2048, 1, 2), 256, 0, stream>>>(q, rep, qb, rb, NE);
  prep_weights<<<dim3(32, 32, 12), dim3(32, 8), 0, stream>>>(
      Wq, Wk, Wv, W1, W2, Ws, wqt, wkt, wvt, w1t, w2t, wst);

  // G1: Qh = q @ Wq  (bf16 -> gh)
  gemm_bf16<1024, 1024, 1024, false, false, false, true><<<dim3(4, 256), 512, 0, stream>>>(
      qb, 0, wqt, 0, gh, 1024, 0, nullptr, 0, nullptr, nullptr);
  // G23: z = sigmoid(Qh * (rep@Wk) / 16) * (rep@Wv)  -> zb
  gemm_g23<<<dim3(8, 256), 512, 0, stream>>>(rb, wkt, wvt, gh, zb);
  // fused MLP: ug = relu(z@W1+b1)@W2+b2  (h1 never leaves LDS)
  gemm_mlp<<<dim3(1, 256, 4), 512, 0, stream>>>(zb, w1t, w2t, b1, b2, ugb);
  // F: out = (q - rep) + ug @ Ws   (residual from bf16 qb/rb)
  gemm_bf16<1024, 1024, 1024, false, false, true, true><<<dim3(4, 256), 512, 0, stream>>>(
      ugb, 0, wst, 0, out, 1024, 0, nullptr, 0, qb, rb);
}

// Round 19
// 1002.897 us; speedup vs baseline: 3.2038x; 1.0004x over previous
//
#include <hip/hip_runtime.h>
#include <hip/hip_bf16.h>

// TreeHopNode: h = q - rep + (per-head MLP(sigmoid(Qh*Kh/16)*Vh)) @ Ws
// N=65536, E=1024, H=4, G=256, MLP=256. bf16 MFMA 16x16x32, f32 accum.
//
// R19 = R18/R13 (validated 1001-1003us, absmax 0.03125) + cvt 16B stores.
// Session ledger (18 rounds): all wins were WORK-REMOVAL (G2+G3 fusion,
// MLP fusion with h1 in LDS, bf16 residual reads, launch merges); the
// K=1024 GEMMs sit at the 2-barrier template's verified ceiling (~31%
// MfmaUtil; 5 schedule variants null, occupancy register-blocked,
// acc[8][8] spills, triple-fusion spills). mlp ~1200 TF eff, cvt at HBM
// floor, F near max(mem, template-compute). Final configuration.

typedef __attribute__((ext_vector_type(8))) short bf16x8;
typedef __attribute__((ext_vector_type(8))) short short8v;
typedef __attribute__((ext_vector_type(4))) float f32x4;

#define AS1 __attribute__((address_space(1)))
#define AS3 __attribute__((address_space(3)))

static __device__ __forceinline__ short f2b(float x) {
  __hip_bfloat16 h = __float2bfloat16(x);
  return __builtin_bit_cast(short, h);
}
static __device__ __forceinline__ float b2f(short s) {
  unsigned u = ((unsigned)(unsigned short)s) << 16;
  return __builtin_bit_cast(float, u);
}

// ---------------- convert f32 -> bf16 (both inputs, one launch) ----------
// 2x float4 read -> one 16B short8 store (G13 coalescing sweet spot).
__global__ void cvt_bf16_2(const float* __restrict__ q, const float* __restrict__ rep,
                           short* __restrict__ qb, short* __restrict__ rb, long n) {
  const float* __restrict__ in = blockIdx.z ? rep : q;
  short* __restrict__ out = blockIdx.z ? rb : qb;
  long i = ((long)blockIdx.x * blockDim.x + threadIdx.x) * 8;
  const long stride = (long)gridDim.x * blockDim.x * 8;
  for (; i < n; i += stride) {
    float4 v0 = *(const float4*)(in + i);
    float4 v1 = *(const float4*)(in + i + 4);
    short8v o = { f2b(v0.x), f2b(v0.y), f2b(v0.z), f2b(v0.w),
                  f2b(v1.x), f2b(v1.y), f2b(v1.z), f2b(v1.w) };
    *(short8v*)(out + i) = o;
  }
}

// ---------------- transpose + convert weights ----------------
__global__ void prep_weights(
    const float* __restrict__ Wq, const float* __restrict__ Wk, const float* __restrict__ Wv,
    const float* __restrict__ W1, const float* __restrict__ W2, const float* __restrict__ Ws,
    short* __restrict__ wqt, short* __restrict__ wkt, short* __restrict__ wvt,
    short* __restrict__ w1t, short* __restrict__ w2t, short* __restrict__ wst)
{
  const int job = blockIdx.z;
  const float* src; short* dst; int R, C;
  if (job < 3)       { src = (job==0)?Wq:((job==1)?Wk:Wv); dst = (job==0)?wqt:((job==1)?wkt:wvt); R = 1024; C = 1024; }
  else if (job == 3) { src = Ws; dst = wst; R = 1024; C = 1024; }
  else if (job < 8)  { int h = job-4; src = W1 + h*65536; dst = w1t + h*65536; R = 256; C = 256; }
  else               { int h = job-8; src = W2 + h*65536; dst = w2t + h*65536; R = 256; C = 256; }
  const int c0 = blockIdx.x * 32, r0 = blockIdx.y * 32;
  if (c0 >= C || r0 >= R) return;
  __shared__ float t[32][33];
  for (int i = threadIdx.y; i < 32; i += 8)
    t[i][threadIdx.x] = src[(long)(r0 + i) * C + c0 + threadIdx.x];
  __syncthreads();
  for (int i = threadIdx.y; i < 32; i += 8)
    dst[(long)(c0 + i) * R + r0 + threadIdx.x] = f2b(t[threadIdx.x][i]);
}

// ---------------- 256x256-tile bf16 GEMM, 4-slot pipeline ----------------
template <int KDIM, int LDA, int LDB, bool RELU, bool BIAS, bool RESID, bool SWZ>
__global__ __launch_bounds__(512, 2) void gemm_bf16(
    const short* __restrict__ A, long zsa,
    const short* __restrict__ Bt, long zsb,
    void* __restrict__ outv, long ldc, long zsc,
    const float* __restrict__ bias, long zsbias,
    const short* __restrict__ qres, const short* __restrict__ rres)
{
  __shared__ __align__(16) short lA[4 * 8192];     // 4 slots of [256][32]
  __shared__ __align__(16) short lB[4 * 8192];
  const int lane = threadIdx.x & 63, wave = threadIdx.x >> 6;
  const int wm = wave >> 2, wn = wave & 3;         // 2M x 4N wave grid
  int bx = blockIdx.x, by = blockIdx.y;
  if (SWZ) {
    const int nbx = gridDim.x;
    const int flat = by * nbx + bx;
    const int chunk = (int)(gridDim.x * gridDim.y) >> 3;
    const int fid = (flat & 7) * chunk + (flat >> 3);
    bx = fid % nbx; by = fid / nbx;
  }
  const long bm = (long)by * 256;
  const int  bn = bx * 256;
  const int  zi = blockIdx.z;

  const short* Ab = A + (long)zi * zsa + bm * LDA;
  const short* Bb = Bt + (long)zi * zsb + (long)bn * LDB;
  constexpr int NS = KDIM / 32;                    // k-slices (32 wide)
  const int g0 = lane >> 4;
  const int arow = wm * 128 + (lane & 15);
  const int bcol = wn * 64 + (lane & 15);

  const char* aP = (const char*)lA + arow * 64 + (((g0 ^ (arow >> 1)) & 3) << 4);
  const char* bP = (const char*)lB + bcol * 64 + (((g0 ^ (bcol >> 1)) & 3) << 4);

  const int rw = lane >> 2;
  const int gg = (lane & 3) ^ ((rw >> 1) & 3);
  const short* Asrc = Ab + (wave * 16 + rw) * LDA + (gg << 3);
  const short* Bsrc = Bb + (wave * 16 + rw) * LDB + (gg << 3);
  short* lAd = lA + wave * 16 * 32;
  short* lBd = lB + wave * 16 * 32;

  auto stA = [&](int slot, int s) {
    const int sc = s < NS ? s : NS - 1;            // tail: clamp SOURCE only
    const short* src = Asrc + sc * 32;
    short* d = lAd + slot * 8192;
    __builtin_amdgcn_global_load_lds((const AS1 void*)src,              (AS3 void*)d,        16, 0, 0);
    __builtin_amdgcn_global_load_lds((const AS1 void*)(src + 128*LDA),  (AS3 void*)(d+4096), 16, 0, 0);
  };
  auto stB = [&](int slot, int s) {
    const int sc = s < NS ? s : NS - 1;
    const short* src = Bsrc + sc * 32;
    short* d = lBd + slot * 8192;
    __builtin_amdgcn_global_load_lds((const AS1 void*)src,              (AS3 void*)d,        16, 0, 0);
    __builtin_amdgcn_global_load_lds((const AS1 void*)(src + 128*LDB),  (AS3 void*)(d+4096), 16, 0, 0);
  };

  stA(0, 0); stB(0, 0);
  stA(1, 1); stB(1, 1);
  stA(2, 2); stB(2, 2);
  asm volatile("s_waitcnt vmcnt(8)" ::: "memory");
  __builtin_amdgcn_s_barrier();

  f32x4 acc[8][4] = {};
  bf16x8 b[4];

#define PHASE(SLOT, MH, LOADB, STAGE_STMT, DOVM)                            \
  {                                                                         \
    if (LOADB) {                                                            \
      _Pragma("unroll")                                                     \
      for (int j = 0; j < 4; ++j)                                           \
        b[j] = *(const bf16x8*)(bP + (SLOT) * 16384 + j * 1024);            \
    }                                                                       \
    bf16x8 a[4];                                                            \
    _Pragma("unroll")                                                       \
    for (int i2 = 0; i2 < 4; ++i2)                                          \
      a[i2] = *(const bf16x8*)(aP + (SLOT) * 16384 + (MH) * 4096 + i2 * 1024); \
    STAGE_STMT;                                                             \
    if (DOVM) asm volatile("s_waitcnt vmcnt(8)" ::: "memory");              \
    asm volatile("" ::: "memory");                                          \
    __builtin_amdgcn_s_barrier();                                           \
    __builtin_amdgcn_s_setprio(1);                                          \
    _Pragma("unroll")                                                       \
    for (int i2 = 0; i2 < 4; ++i2)                                          \
      _Pragma("unroll")                                                     \
      for (int j = 0; j < 4; ++j)                                           \
        acc[(MH) * 4 + i2][j] = __builtin_amdgcn_mfma_f32_16x16x32_bf16(    \
            a[i2], b[j], acc[(MH) * 4 + i2][j], 0, 0, 0);                   \
    __builtin_amdgcn_s_setprio(0);                                          \
    asm volatile("" ::: "memory");                                          \
    __builtin_amdgcn_s_barrier();                                           \
  }

  for (int s = 0; s < NS; s += 4) {
    PHASE(0, 0, true,  stA(3, s + 3), false) PHASE(0, 1, false, stB(3, s + 3), true)
    PHASE(1, 0, true,  stA(0, s + 4), false) PHASE(1, 1, false, stB(0, s + 4), true)
    PHASE(2, 0, true,  stA(1, s + 5), false) PHASE(2, 1, false, stB(1, s + 5), true)
    PHASE(3, 0, true,  stA(2, s + 6), false) PHASE(3, 1, false, stB(2, s + 6), true)
  }
#undef PHASE

  // epilogue; C/D layout: col=lane&15, row=(lane>>4)*4+reg (m89)
  #pragma unroll
  for (int i = 0; i < 8; ++i)
    #pragma unroll
    for (int j = 0; j < 4; ++j)
      #pragma unroll
      for (int r = 0; r < 4; ++r) {
        const int rl = wm * 128 + i * 16 + ((lane >> 4) << 2) + r;
        const int cl = wn * 64 + j * 16 + (lane & 15);
        float v = acc[i][j][r];
        if (BIAS) v += bias[(long)zi * zsbias + bn + cl];
        if (RELU) v = v > 0.0f ? v : 0.0f;
        const long row = bm + rl;
        const long gi = (long)zi * zsc + row * ldc + bn + cl;
        if (RESID) {
          ((float*)outv)[gi] = b2f(qres[gi]) - b2f(rres[gi]) + v;
        } else {
          ((short*)outv)[gi] = f2b(v);
        }
      }
}

// ------------- merged G2+G3: z = sigmoid(Qh*Kh/16) * Vh -----------------
__global__ __launch_bounds__(512, 2) void gemm_g23(
    const short* __restrict__ rb, const short* __restrict__ wkt,
    const short* __restrict__ wvt, const short* __restrict__ gh,
    short* __restrict__ zb)
{
  __shared__ __align__(16) short lA[4 * 8192];
  __shared__ __align__(16) short lK[4 * 4096];
  __shared__ __align__(16) short lV[4 * 4096];
  const int lane = threadIdx.x & 63, wave = threadIdx.x >> 6;
  const int wm = wave >> 2, wn = wave & 3;
  int bx = blockIdx.x, by = blockIdx.y;
  {
    const int flat = by * 8 + bx;
    const int chunk = (int)(gridDim.x * gridDim.y) >> 3;
    const int fid = (flat & 7) * chunk + (flat >> 3);
    bx = fid & 7; by = fid >> 3;
  }
  const long bm = (long)by * 256;
  const int  bn = bx * 128;

  const short* Ab = rb + bm * 1024;
  const short* Kb = wkt + (long)bn * 1024;
  const short* Vb = wvt + (long)bn * 1024;
  constexpr int NS = 32;
  const int g0 = lane >> 4;
  const int arow = wm * 128 + (lane & 15);
  const int bcol = wn * 32 + (lane & 15);

  const char* aP = (const char*)lA + arow * 64 + (((g0 ^ (arow >> 1)) & 3) << 4);
  const char* kP = (const char*)lK + bcol * 64 + (((g0 ^ (bcol >> 1)) & 3) << 4);
  const char* vP = (const char*)lV + bcol * 64 + (((g0 ^ (bcol >> 1)) & 3) << 4);

  const int rw = lane >> 2;
  const int gg = (lane & 3) ^ ((rw >> 1) & 3);
  const short* Asrc = Ab + (wave * 16 + rw) * 1024 + (gg << 3);
  const short* Ksrc = Kb + (wave * 16 + rw) * 1024 + (gg << 3);
  const short* Vsrc = Vb + (wave * 16 + rw) * 1024 + (gg << 3);
  short* lAd = lA + wave * 16 * 32;
  short* lKd = lK + wave * 16 * 32;
  short* lVd = lV + wave * 16 * 32;

  auto stA = [&](int slot, int s) {
    const int sc = s < NS ? s : NS - 1;
    const short* src = Asrc + sc * 32;
    short* d = lAd + slot * 8192;
    __builtin_amdgcn_global_load_lds((const AS1 void*)src,               (AS3 void*)d,        16, 0, 0);
    __builtin_amdgcn_global_load_lds((const AS1 void*)(src + 128*1024),  (AS3 void*)(d+4096), 16, 0, 0);
  };
  auto stKV = [&](int slot, int s) {
    const int sc = s < NS ? s : NS - 1;
    __builtin_amdgcn_global_load_lds((const AS1 void*)(Ksrc + sc * 32), (AS3 void*)(lKd + slot * 4096), 16, 0, 0);
    __builtin_amdgcn_global_load_lds((const AS1 void*)(Vsrc + sc * 32), (AS3 void*)(lVd + slot * 4096), 16, 0, 0);
  };

  stA(0, 0); stKV(0, 0);
  stA(1, 1); stKV(1, 1);
  stA(2, 2); stKV(2, 2);
  asm volatile("s_waitcnt vmcnt(8)" ::: "memory");
  __builtin_amdgcn_s_barrier();

  f32x4 ack[8][2] = {};
  f32x4 acv[8][2] = {};
  bf16x8 bk[2], bv[2];

#define PHASEG(SLOT, MH, LOADB, STAGE_STMT, DOVM)                           \
  {                                                                         \
    if (LOADB) {                                                            \
      _Pragma("unroll")                                                     \
      for (int j = 0; j < 2; ++j) {                                         \
        bk[j] = *(const bf16x8*)(kP + (SLOT) * 8192 + j * 1024);            \
        bv[j] = *(const bf16x8*)(vP + (SLOT) * 8192 + j * 1024);            \
      }                                                                     \
    }                                                                       \
    bf16x8 a[4];                                                            \
    _Pragma("unroll")                                                       \
    for (int i2 = 0; i2 < 4; ++i2)                                          \
      a[i2] = *(const bf16x8*)(aP + (SLOT) * 16384 + (MH) * 4096 + i2 * 1024); \
    STAGE_STMT;                                                             \
    if (DOVM) asm volatile("s_waitcnt vmcnt(8)" ::: "memory");              \
    asm volatile("" ::: "memory");                                          \
    __builtin_amdgcn_s_barrier();                                           \
    __builtin_amdgcn_s_setprio(1);                                          \
    _Pragma("unroll")                                                       \
    for (int i2 = 0; i2 < 4; ++i2)                                          \
      _Pragma("unroll")                                                     \
      for (int j = 0; j < 2; ++j) {                                         \
        ack[(MH) * 4 + i2][j] = __builtin_amdgcn_mfma_f32_16x16x32_bf16(    \
            a[i2], bk[j], ack[(MH) * 4 + i2][j], 0, 0, 0);                  \
        acv[(MH) * 4 + i2][j] = __builtin_amdgcn_mfma_f32_16x16x32_bf16(    \
            a[i2], bv[j], acv[(MH) * 4 + i2][j], 0, 0, 0);                  \
      }                                                                     \
    __builtin_amdgcn_s_setprio(0);                                          \
    asm volatile("" ::: "memory");                                          \
    __builtin_amdgcn_s_barrier();                                           \
  }

  for (int s = 0; s < NS; s += 4) {
    PHASEG(0, 0, true,  stA(3, s + 3), false) PHASEG(0, 1, false, stKV(3, s + 3), true)
    PHASEG(1, 0, true,  stA(0, s + 4), false) PHASEG(1, 1, false, stKV(0, s + 4), true)
    PHASEG(2, 0, true,  stA(1, s + 5), false) PHASEG(2, 1, false, stKV(1, s + 5), true)
    PHASEG(3, 0, true,  stA(2, s + 6), false) PHASEG(3, 1, false, stKV(2, s + 6), true)
  }
#undef PHASEG

  #pragma unroll
  for (int i = 0; i < 8; ++i)
    #pragma unroll
    for (int j = 0; j < 2; ++j)
      #pragma unroll
      for (int r = 0; r < 4; ++r) {
        const int rl = wm * 128 + i * 16 + ((lane >> 4) << 2) + r;
        const int cl = wn * 32 + j * 16 + (lane & 15);
        const long gi = (bm + rl) * 1024 + bn + cl;
        const float x = b2f(gh[gi]) * ack[i][j][r] * 0.0625f;
        const float gate = 1.0f / (1.0f + __expf(-x));
        zb[gi] = f2b(gate * acv[i][j][r]);
      }
}

// ------------- fused MLP: ug = relu(z_h @ W1_h + b1) @ W2_h + b2 --------
__global__ __launch_bounds__(512) void gemm_mlp(
    const short* __restrict__ zb, const short* __restrict__ w1t,
    const short* __restrict__ w2t, const float* __restrict__ b1,
    const float* __restrict__ b2, short* __restrict__ ug)
{
  __shared__ __align__(16) char smem[163840];
  short* lA = (short*)smem;                        // pass1: 4 x 16KB
  short* lB = (short*)(smem + 65536);              // pass1: 4 x 16KB
  short* stash = (short*)smem;                     // h1: 128KB (after pass1)
  short* w2b = (short*)(smem + 131072);            // pass2 B: 2 x 16KB

  const int lane = threadIdx.x & 63, wave = threadIdx.x >> 6;
  const int wm = wave >> 2, wn = wave & 3;
  const long bm = (long)blockIdx.y * 256;
  const int head = blockIdx.z;

  const int g0 = lane >> 4;
  const int arow = wm * 128 + (lane & 15);
  const int bcol = wn * 64 + (lane & 15);
  const int rw = lane >> 2;
  const int gg = (lane & 3) ^ ((rw >> 1) & 3);

  // ---------- pass 1: h1 = relu(z_h @ W1_h + b1) ----------
  {
    const short* Ab = zb + bm * 1024 + head * 256;
    const short* Bb = w1t + head * 65536;
    const char* aP = (const char*)lA + arow * 64 + (((g0 ^ (arow >> 1)) & 3) << 4);
    const char* bP = (const char*)lB + bcol * 64 + (((g0 ^ (bcol >> 1)) & 3) << 4);
    const short* Asrc = Ab + (wave * 16 + rw) * 1024 + (gg << 3);
    const short* Bsrc = Bb + (wave * 16 + rw) * 256 + (gg << 3);
    short* lAd = lA + wave * 16 * 32;
    short* lBd = lB + wave * 16 * 32;

    auto stA = [&](int slot, int s) {
      const int sc = s < 8 ? s : 7;
      const short* src = Asrc + sc * 32;
      short* d = lAd + slot * 8192;
      __builtin_amdgcn_global_load_lds((const AS1 void*)src,              (AS3 void*)d,        16, 0, 0);
      __builtin_amdgcn_global_load_lds((const AS1 void*)(src + 128*1024), (AS3 void*)(d+4096), 16, 0, 0);
    };
    auto stB = [&](int slot, int s) {
      const int sc = s < 8 ? s : 7;
      const short* src = Bsrc + sc * 32;
      short* d = lBd + slot * 8192;
      __builtin_amdgcn_global_load_lds((const AS1 void*)src,              (AS3 void*)d,        16, 0, 0);
      __builtin_amdgcn_global_load_lds((const AS1 void*)(src + 128*256),  (AS3 void*)(d+4096), 16, 0, 0);
    };

    stA(0, 0); stB(0, 0);
    stA(1, 1); stB(1, 1);
    stA(2, 2); stB(2, 2);
    asm volatile("s_waitcnt vmcnt(8)" ::: "memory");
    __builtin_amdgcn_s_barrier();

    f32x4 acc[8][4] = {};
    bf16x8 b[4];

#define PHASE1(SLOT, MH, LOADB, STAGE_STMT, DOVM)                           \
    {                                                                       \
      if (LOADB) {                                                          \
        _Pragma("unroll")                                                   \
        for (int j = 0; j < 4; ++j)                                         \
          b[j] = *(const bf16x8*)(bP + (SLOT) * 16384 + j * 1024);          \
      }                                                                     \
      bf16x8 a[4];                                                          \
      _Pragma("unroll")                                                     \
      for (int i2 = 0; i2 < 4; ++i2)                                        \
        a[i2] = *(const bf16x8*)(aP + (SLOT) * 16384 + (MH) * 4096 + i2 * 1024); \
      STAGE_STMT;                                                           \
      if (DOVM) asm volatile("s_waitcnt vmcnt(8)" ::: "memory");            \
      asm volatile("" ::: "memory");                                        \
      __builtin_amdgcn_s_barrier();                                         \
      __builtin_amdgcn_s_setprio(1);                                        \
      _Pragma("unroll")                                                     \
      for (int i2 = 0; i2 < 4; ++i2)                                        \
        _Pragma("unroll")                                                   \
        for (int j = 0; j < 4; ++j)                                         \
          acc[(MH) * 4 + i2][j] = __builtin_amdgcn_mfma_f32_16x16x32_bf16(  \
              a[i2], b[j], acc[(MH) * 4 + i2][j], 0, 0, 0);                 \
      __builtin_amdgcn_s_setprio(0);                                        \
      asm volatile("" ::: "memory");                                        \
      __builtin_amdgcn_s_barrier();                                         \
    }

    for (int s = 0; s < 8; s += 4) {
      PHASE1(0, 0, true,  stA(3, s + 3), false) PHASE1(0, 1, false, stB(3, s + 3), true)
      PHASE1(1, 0, true,  stA(0, s + 4), false) PHASE1(1, 1, false, stB(0, s + 4), true)
      PHASE1(2, 0, true,  stA(1, s + 5), false) PHASE1(2, 1, false, stB(1, s + 5), true)
      PHASE1(3, 0, true,  stA(2, s + 6), false) PHASE1(3, 1, false, stB(2, s + 6), true)
    }
#undef PHASE1

    __syncthreads();     // all pass-1 LDS reads done before stash overwrite
    #pragma unroll
    for (int i = 0; i < 8; ++i)
      #pragma unroll
      for (int j = 0; j < 4; ++j)
        #pragma unroll
        for (int r = 0; r < 4; ++r) {
          const int rl = wm * 128 + i * 16 + ((lane >> 4) << 2) + r;
          const int cl = wn * 64 + j * 16 + (lane & 15);
          float v = acc[i][j][r] + b1[head * 256 + cl];
          v = v > 0.0f ? v : 0.0f;
          stash[rl * 256 + ((((cl >> 3) ^ rl) & 31) << 3) + (cl & 7)] = f2b(v);
        }
    __syncthreads();     // stash complete before pass-2 reads
  }

  // ---------- pass 2: ug = h1 @ W2_h + b2 ----------
  {
    const short* Wb = w2t + head * 65536;
    const short* Bsrc2 = Wb + (wave * 16 + rw) * 256 + (gg << 3);
    short* lBd2 = w2b + wave * 16 * 32;
    const char* b2P = (const char*)w2b + bcol * 64 + (((g0 ^ (bcol >> 1)) & 3) << 4);

    auto stW = [&](int slot, int s) {
      const int sc = s < 8 ? s : 7;
      const short* src = Bsrc2 + sc * 32;
      short* d = lBd2 + slot * 8192;
      __builtin_amdgcn_global_load_lds((const AS1 void*)src,             (AS3 void*)d,        16, 0, 0);
      __builtin_amdgcn_global_load_lds((const AS1 void*)(src + 128*256), (AS3 void*)(d+4096), 16, 0, 0);
    };

    stW(0, 0);
    asm volatile("s_waitcnt vmcnt(0)" ::: "memory");
    __builtin_amdgcn_s_barrier();

    f32x4 acc2[8][4] = {};
    bf16x8 br[4];

    for (int s = 0; s < 8; ++s) {
      const int sl = s & 1;
      const int ks = s * 4 + g0;       // 16B k-slot index in stash

#define PHASE2(MH, LOADB, STAGE_STMT, DOVM)                                 \
      {                                                                     \
        if (LOADB) {                                                        \
          _Pragma("unroll")                                                 \
          for (int j = 0; j < 4; ++j)                                       \
            br[j] = *(const bf16x8*)(b2P + sl * 16384 + j * 1024);          \
        }                                                                   \
        bf16x8 a[4];                                                        \
        _Pragma("unroll")                                                   \
        for (int i2 = 0; i2 < 4; ++i2) {                                    \
          const int row = arow + (MH) * 64 + i2 * 16;                       \
          a[i2] = *(const bf16x8*)(stash + row * 256 + (((ks ^ row) & 31) << 3)); \
        }                                                                   \
        STAGE_STMT;                                                         \
        if (DOVM) asm volatile("s_waitcnt vmcnt(0)" ::: "memory");          \
        asm volatile("" ::: "memory");                                      \
        __builtin_amdgcn_s_barrier();                                       \
        __builtin_amdgcn_s_setprio(1);                                      \
        _Pragma("unroll")                                                   \
        for (int i2 = 0; i2 < 4; ++i2)                                      \
          _Pragma("unroll")                                                 \
          for (int j = 0; j < 4; ++j)                                       \
            acc2[(MH) * 4 + i2][j] = __builtin_amdgcn_mfma_f32_16x16x32_bf16( \
                a[i2], br[j], acc2[(MH) * 4 + i2][j], 0, 0, 0);             \
        __builtin_amdgcn_s_setprio(0);                                      \
        asm volatile("" ::: "memory");                                      \
        __builtin_amdgcn_s_barrier();                                       \
      }

      PHASE2(0, true,  stW(sl ^ 1, s + 1), false)
      PHASE2(1, false, {}, true)
#undef PHASE2
    }

    #pragma unroll
    for (int i = 0; i < 8; ++i)
      #pragma unroll
      for (int j = 0; j < 4; ++j)
        #pragma unroll
        for (int r = 0; r < 4; ++r) {
          const int rl = wm * 128 + i * 16 + ((lane >> 4) << 2) + r;
          const int cl = wn * 64 + j * 16 + (lane & 15);
          const float v = acc2[i][j][r] + b2[head * 256 + cl];
          ug[(bm + rl) * 1024 + head * 256 + cl] = f2b(v);
        }
  }
}

extern "C" void kernel_launch(void* const* d_in, const int* in_sizes, int n_in,
                              void* d_out, int out_size, void* d_ws, size_t ws_size,
                              hipStream_t stream) {
  const float* q   = (const float*)d_in[0];
  const float* rep = (const float*)d_in[1];
  const float* Wq  = (const float*)d_in[2];
  const float* Wk  = (const float*)d_in[3];
  const float* Wv  = (const float*)d_in[4];
  const float* W1  = (const float*)d_in[5];
  const float* b1  = (const float*)d_in[6];
  const float* W2  = (const float*)d_in[7];
  const float* b2  = (const float*)d_in[8];
  const float* Ws  = (const float*)d_in[9];
  float* out = (float*)d_out;

  const long NE = 67108864L;   // 65536 * 1024
  char* ws = (char*)d_ws;
  // 4 x 128 MiB slots:
  //   s0: qb (cvt..F)   s1: rb (cvt..F)
  //   s2: gh (G1..g23) -> ug (mlp..F)
  //   s3: zb (g23..mlp)
  short* qb  = (short*)(ws);
  short* rb  = (short*)(ws + NE * 2);
  short* gh  = (short*)(ws + NE * 4);
  short* zb  = (short*)(ws + NE * 6);
  short* ugb = gh;
  char*  wp  = ws + NE * 8;
  short* wqt = (short*)(wp);                 // 2 MiB each
  short* wkt = (short*)(wp + 2097152);
  short* wvt = (short*)(wp + 4194304);
  short* wst = (short*)(wp + 6291456);
  short* w1t = (short*)(wp + 8388608);       // 512 KiB
  short* w2t = (short*)(wp + 8912896);       // 512 KiB

  cvt_bf16_2<<<dim3(2048, 1, 2), 256, 0, stream>>>(q, rep, qb, rb, NE);
  prep_weights<<<dim3(32, 32, 12), dim3(32, 8), 0, stream>>>(
      Wq, Wk, Wv, W1, W2, Ws, wqt, wkt, wvt, w1t, w2t, wst);

  // G1: Qh = q @ Wq  (bf16 -> gh)
  gemm_bf16<1024, 1024, 1024, false, false, false, true><<<dim3(4, 256), 512, 0, stream>>>(
      qb, 0, wqt, 0, gh, 1024, 0, nullptr, 0, nullptr, nullptr);
  // G23: z = sigmoid(Qh * (rep@Wk) / 16) * (rep@Wv)  -> zb
  gemm_g23<<<dim3(8, 256), 512, 0, stream>>>(rb, wkt, wvt, gh, zb);
  // fused MLP: ug = relu(z@W1+b1)@W2+b2  (h1 never leaves LDS)
  gemm_mlp<<<dim3(1, 256, 4), 512, 0, stream>>>(zb, w1t, w2t, b1, b2, ugb);
  // F: out = (q - rep) + ug @ Ws   (residual from bf16 qb/rb)
  gemm_bf16<1024, 1024, 1024, false, false, true, true><<<dim3(4, 256), 512, 0, stream>>>(
      ugb, 0, wst, 0, out, 1024, 0, nullptr, 0, qb, rb);
}